// Round 15
// baseline (67.637 us; speedup 1.0000x reference)
//
#include <hip/hip_runtime.h>
#include <stdint.h>

#define BB 256
#define CC 64
#define CVV 4
#define LL 2048
#define NRG 17   // rows per gather block (68 / 4 groups)
#define STAGE_BYTES ((size_t)BB * LL * 4)

// Padded key indexing for the bitonic (neutral-to-positive, kept from R14).
#define KIDX(i) ((i) + ((i) >> 4))

// LDS-only barrier: orders ds ops across waves WITHOUT draining vmcnt.
#define SBAR_LDS() do { \
    asm volatile("s_waitcnt lgkmcnt(0)" ::: "memory"); \
    __builtin_amdgcn_s_barrier(); \
    __builtin_amdgcn_sched_barrier(0); \
  } while (0)

__device__ __forceinline__ void ce_desc(unsigned long long* key, int i, int j,
                                        bool descBlk) {
  unsigned long long a = key[KIDX(i)], c = key[KIDX(j)];
  bool sw = descBlk ? (a < c) : (a > c);
  if (sw) { key[KIDX(i)] = c; key[KIDX(j)] = a; }
}

// ---------------------------------------------------------------------------
// Kernel 1: per-batch stable descending argsort (R14's sort, standalone).
// Writes stage ints (idx | masked<<11 | keep<<12) as int4 and, when
// mout != nullptr, the final mask_t floats as float4.
// ---------------------------------------------------------------------------
__global__ __launch_bounds__(512) void sortperm_kernel(const void* mask,
                                                       const float* rnd,
                                                       int* stage,
                                                       float* mout) {
  __shared__ unsigned long long key[2176];  // 2048 + pads
  __shared__ int wcnt[8];

  const int b = blockIdx.x;
  const int tid = threadIdx.x;
  const int w = tid >> 6;
  const int lane = tid & 63;
  const unsigned* m32 = (const unsigned*)mask;

  // scalar-load layout detect (uniform address -> s_load)
  unsigned acc = 0;
#pragma unroll
  for (int j = 0; j < 16; ++j) acc |= m32[(size_t)b * 512 + j];
  const bool is_byte = (acc != 0u) && (acc != 1u) && (acc != 0x3F800000u);

  float rv[4]; unsigned mw[4];
#pragma unroll
  for (int k = 0; k < 4; ++k) {
    const int l = tid + 512 * k;
    rv[k] = rnd[(size_t)b * LL + l];
    mw[k] = is_byte ? m32[(size_t)b * 512 + (l >> 2)]
                    : m32[(size_t)b * LL + l];
  }

  const int sh8 = 8 * (tid & 3);
  int local = 0;
#pragma unroll
  for (int k = 0; k < 4; ++k) {
    const int l = tid + 512 * k;
    const bool m = is_byte ? (((mw[k] >> sh8) & 0xFFu) != 0u) : (mw[k] != 0u);
    float rf = m ? -1.0f : rv[k];
    unsigned u = __float_as_uint(rf);
    u = (u & 0x80000000u) ? ~u : (u | 0x80000000u);  // order-preserving map
    key[KIDX(l)] = ((unsigned long long)u << 32) | (unsigned)(LL - 1 - l);
    local += m ? 1 : 0;
  }
#pragma unroll
  for (int off = 32; off > 0; off >>= 1) local += __shfl_down(local, off, 64);
  if (lane == 0) wcnt[w] = local;
  SBAR_LDS();

  // bitonic sort, descending; wave w owns key[w*256 .. w*256+255]
  for (int size = 2; size <= 256; size <<= 1) {
    for (int stride = size >> 1; stride > 0; stride >>= 1) {
#pragma unroll
      for (int pp = 0; pp < 2; ++pp) {
        int p = w * 128 + pp * 64 + lane;
        int i = ((p & ~(stride - 1)) << 1) | (p & (stride - 1));
        ce_desc(key, i, i + stride, (i & size) == 0);
      }
      __builtin_amdgcn_wave_barrier();
    }
  }
  SBAR_LDS();
  for (int size = 512; size <= 2048; size <<= 1) {
    for (int stride = size >> 1; stride >= 256; stride >>= 1) {
      for (int t = tid; t < LL / 2; t += 512) {
        int i = ((t & ~(stride - 1)) << 1) | (t & (stride - 1));
        ce_desc(key, i, i + stride, (i & size) == 0);
      }
      SBAR_LDS();
    }
    for (int stride = 128; stride > 0; stride >>= 1) {
#pragma unroll
      for (int pp = 0; pp < 2; ++pp) {
        int p = w * 128 + pp * 64 + lane;
        int i = ((p & ~(stride - 1)) << 1) | (p & (stride - 1));
        ce_desc(key, i, i + stride, (i & size) == 0);
      }
      __builtin_amdgcn_wave_barrier();
    }
    SBAR_LDS();
  }

  const int cnt = wcnt[0] + wcnt[1] + wcnt[2] + wcnt[3] +
                  wcnt[4] + wcnt[5] + wcnt[6] + wcnt[7];
  const int maxlen = cnt > 1 ? cnt : 1;              // jnp.maximum(count, 1)
  const unsigned ordNeg1 = ~__float_as_uint(-1.0f);  // ord(-1.0)
  int sv[4]; float mf[4];
#pragma unroll
  for (int k = 0; k < 4; ++k) {
    const int j = tid * 4 + k;
    unsigned long long k2 = key[KIDX(j)];
    int idx = (LL - 1) - (int)(unsigned)(k2 & 0xFFFFFFFFull);
    bool masked = ((unsigned)(k2 >> 32)) == ordNeg1;
    bool keep = j < maxlen;
    sv[k] = idx | (masked ? (1 << 11) : 0) | (keep ? (1 << 12) : 0);
    mf[k] = (keep && masked) ? 1.0f : 0.0f;
  }
  ((int4*)(stage + (size_t)b * LL))[tid] = make_int4(sv[0], sv[1], sv[2], sv[3]);
  if (mout)
    ((float4*)(mout + (size_t)b * LL))[tid] =
        make_float4(mf[0], mf[1], mf[2], mf[3]);
}

// ---------------------------------------------------------------------------
// Kernel 2: gather, 4 independent blocks per batch (1024 blocks = 4/CU, each
// 256 threads = 4 waves, 32 KB LDS). Block (b,g) owns rows g*17..g*17+16.
// Register-staged: 8 named float4 regs hold 2 in-flight rows (lo+hi chunk
// per row), 4-slot LDS ring, TWO rows per LDS-only barrier, distance-4
// reload, compiler-managed counted vmcnt. No global_load_lds, no vmcnt
// drain. Four independent barrier domains per CU keep the HBM read+write
// streams fed continuously (de-bursted).
// ---------------------------------------------------------------------------
__global__ __launch_bounds__(256) void gather_kernel(
    const float* __restrict__ x, const float* __restrict__ v,
    const int* __restrict__ stage, float* __restrict__ xo,
    float* __restrict__ vo) {
  __shared__ float ring[4][LL];  // 32 KB
  const int b = blockIdx.x >> 2;
  const int g = blockIdx.x & 3;
  const int tid = threadIdx.x;

  const int4* st4 = (const int4*)(stage + (size_t)b * LL);
  const int4 sLo = st4[tid];         // perm for j = 4tid..4tid+3
  const int4 sHi = st4[tid + 256];   // perm for j = 1024+4tid..+3

  const float* const xs = x + (size_t)b * CC * LL;
  const float* const vs = v + (size_t)b * CVV * LL;
  float* const xd = xo + (size_t)b * CC * LL;
  float* const vd = vo + (size_t)b * CVV * LL;

#define SRCROW(rr) ((g * NRG + (rr)) < CC \
    ? xs + (size_t)(g * NRG + (rr)) * LL \
    : vs + (size_t)(g * NRG + (rr) - CC) * LL)
#define DSTROW(rr) ((g * NRG + (rr)) < CC \
    ? xd + (size_t)(g * NRG + (rr)) * LL \
    : vd + (size_t)(g * NRG + (rr) - CC) * LL)

  // prefetch rows 0..3 (lo+hi chunks) into NAMED registers
  float4 A0 = ((const float4*)SRCROW(0))[tid];
  float4 B0 = ((const float4*)SRCROW(0))[tid + 256];
  float4 A1 = ((const float4*)SRCROW(1))[tid];
  float4 B1 = ((const float4*)SRCROW(1))[tid + 256];
  float4 A2 = ((const float4*)SRCROW(2))[tid];
  float4 B2 = ((const float4*)SRCROW(2))[tid + 256];
  float4 A3 = ((const float4*)SRCROW(3))[tid];
  float4 B3 = ((const float4*)SRCROW(3))[tid + 256];

#define GROW(q, rr) do { \
    const float* _b = &ring[q][0]; \
    float4* _o = (float4*)DSTROW(rr); \
    float4 o; \
    o.x = (sLo.x & (1 << 12)) ? _b[sLo.x & 0x7FF] : 0.0f; \
    o.y = (sLo.y & (1 << 12)) ? _b[sLo.y & 0x7FF] : 0.0f; \
    o.z = (sLo.z & (1 << 12)) ? _b[sLo.z & 0x7FF] : 0.0f; \
    o.w = (sLo.w & (1 << 12)) ? _b[sLo.w & 0x7FF] : 0.0f; \
    _o[tid] = o; \
    o.x = (sHi.x & (1 << 12)) ? _b[sHi.x & 0x7FF] : 0.0f; \
    o.y = (sHi.y & (1 << 12)) ? _b[sHi.y & 0x7FF] : 0.0f; \
    o.z = (sHi.z & (1 << 12)) ? _b[sHi.z & 0x7FF] : 0.0f; \
    o.w = (sHi.w & (1 << 12)) ? _b[sHi.w & 0x7FF] : 0.0f; \
    _o[tid + 256] = o; \
  } while (0)

  // Pair pp: ds_write rows {2pp,2pp+1}, ONE barrier, reload regs with rows
  // +4, gather+store the 2 rows. Ring safety: pair pp writes slots {0,1} or
  // {2,3}, last read at pair pp-2, separated by barrier pp-1.
#define PAIR(pp, PA, PB, QA, QB) do { \
    constexpr int r0 = 2 * (pp), r1 = r0 + 1; \
    constexpr int q0 = (2 * (pp)) & 3, q1 = q0 + 1; \
    ((float4*)&ring[q0][0])[tid] = PA; \
    ((float4*)&ring[q0][0])[tid + 256] = PB; \
    ((float4*)&ring[q1][0])[tid] = QA; \
    ((float4*)&ring[q1][0])[tid + 256] = QB; \
    SBAR_LDS(); \
    if constexpr (r0 + 4 < NRG) { \
      PA = ((const float4*)SRCROW(r0 + 4))[tid]; \
      PB = ((const float4*)SRCROW(r0 + 4))[tid + 256]; \
    } \
    if constexpr (r1 + 4 < NRG) { \
      QA = ((const float4*)SRCROW(r1 + 4))[tid]; \
      QB = ((const float4*)SRCROW(r1 + 4))[tid + 256]; \
    } \
    GROW(q0, r0); \
    GROW(q1, r1); \
  } while (0)

  PAIR(0, A0, B0, A1, B1);   // rows 0,1   ; reload 4,5
  PAIR(1, A2, B2, A3, B3);   // rows 2,3   ; reload 6,7
  PAIR(2, A0, B0, A1, B1);   // rows 4,5   ; reload 8,9
  PAIR(3, A2, B2, A3, B3);   // rows 6,7   ; reload 10,11
  PAIR(4, A0, B0, A1, B1);   // rows 8,9   ; reload 12,13
  PAIR(5, A2, B2, A3, B3);   // rows 10,11 ; reload 14,15
  PAIR(6, A0, B0, A1, B1);   // rows 12,13 ; reload 16 (row 17 guarded off)
  PAIR(7, A2, B2, A3, B3);   // rows 14,15 ; no reload
  // epilogue: row 16 (in A0/B0 since pair 6)
  ((float4*)&ring[0][0])[tid] = A0;
  ((float4*)&ring[0][0])[tid + 256] = B0;
  SBAR_LDS();
  GROW(0, 16);
#undef PAIR
#undef GROW
#undef SRCROW
#undef DSTROW
}

// ---------------------------------------------------------------------------
// Kernel 3 (fallback when ws too small; stage aliases mask output region).
// ---------------------------------------------------------------------------
__global__ __launch_bounds__(256) void maskout_kernel(int* stage, float* mout) {
  const int i = blockIdx.x * 256 + threadIdx.x;
  int s = stage[i];
  mout[i] = ((s & (1 << 12)) && (s & (1 << 11))) ? 1.0f : 0.0f;
}

extern "C" void kernel_launch(void* const* d_in, const int* in_sizes, int n_in,
                              void* d_out, int out_size, void* d_ws, size_t ws_size,
                              hipStream_t stream) {
  const float* x    = (const float*)d_in[0];
  const float* v    = (const float*)d_in[1];
  const void*  mask = d_in[2];
  const float* rnd  = (const float*)d_in[3];

  float* xo = (float*)d_out;                  // B*C*L
  float* vo = xo + (size_t)BB * CC * LL;      // B*CV*L
  float* mo = vo + (size_t)BB * CVV * LL;     // B*1*L

  const bool use_ws = ws_size >= STAGE_BYTES;
  int* stage = use_ws ? (int*)d_ws : (int*)mo;

  sortperm_kernel<<<BB, 512, 0, stream>>>(mask, rnd, stage,
                                          use_ws ? mo : nullptr);
  gather_kernel<<<BB * 4, 256, 0, stream>>>(x, v, stage, xo, vo);
  if (!use_ws)
    maskout_kernel<<<(BB * LL) / 256, 256, 0, stream>>>(stage, mo);
}

// Round 16
// 66.784 us; speedup vs baseline: 1.0128x; 1.0128x over previous
//
#include <hip/hip_runtime.h>
#include <stdint.h>

#define BB 256
#define CC 64
#define CVV 4
#define LL 2048
#define NR (CC + CVV)   // 68 rows per block (= per batch)

// Padded key indexing for the bitonic.
#define KIDX(i) ((i) + ((i) >> 4))

#define WAITV(n) asm volatile("s_waitcnt vmcnt(" #n ")" ::: "memory")
// LDS-only barrier: orders ds ops across waves WITHOUT draining vmcnt.
#define SBAR_LDS() do { \
    asm volatile("s_waitcnt lgkmcnt(0)" ::: "memory"); \
    __builtin_amdgcn_s_barrier(); \
    __builtin_amdgcn_sched_barrier(0); \
  } while (0)

// Volatile asm load: backend cannot sink/remat it; result regs stay live.
// NOTE: compiler does NOT track vmcnt for these - consumer needs manual WAITV.
#define ALOAD(REG, PTR) \
  asm volatile("global_load_dwordx4 %0, %1, off" : "=v"(REG) : "v"(PTR))

__device__ __forceinline__ void ce_desc(unsigned long long* key, int i, int j,
                                        bool descBlk) {
  unsigned long long a = key[KIDX(i)], c = key[KIDX(j)];
  bool sw = descBlk ? (a < c) : (a > c);
  if (sw) { key[KIDX(i)] = c; key[KIDX(j)] = a; }
}

// ---------------------------------------------------------------------------
// One block per batch (256 blocks = 1/CU, 512 threads = 8 waves).
// Phase 1: bitonic argsort of rand_f (composite keys ord(rand_f)<<32 |
//   (L-1-idx), wave-segment optimized, LDS-only barriers, padded keys).
// Phase 2: register-staged gather, 16 named float4 regs for rows 0..15
//   loaded via ASM VOLATILE global_load_dwordx4 BEFORE the sort (R14's plain
//   loads were sunk by the compiler: VGPR=52 < the 64 the prefetch needs;
//   asm volatile cannot be sunk -> 32 MB chip-wide streams under the sort).
//   8-slot LDS ring (64 KB), four rows per barrier (17 quads), reload
//   distance 16 (quads 4+ use plain loads: compiler-tracked vmcnt).
//   Quads 0-3 consume asm-defined regs -> manual conservative WAITV
//   (13/9/5/1): counts only known-newer ops (12/8/4/0 prefetch loads +
//   1 mask store); any compiler-issued ops are newer -> smaller N = safe.
// ---------------------------------------------------------------------------
__global__ __launch_bounds__(512) void trimmer_kernel(
    const float* __restrict__ x, const float* __restrict__ v,
    const void* __restrict__ mask, const float* __restrict__ rnd,
    float* __restrict__ xo, float* __restrict__ vo, float* __restrict__ mo) {
  __shared__ union {
    unsigned long long key[2176];  // 2048 + 128 pads = 17 KB
    float ring[8][LL];             // 8 x 8 KB = 64 KB
  } sh;
  __shared__ int wcnt[8];

  const int b = blockIdx.x;
  const int tid = threadIdx.x;
  const int w = tid >> 6;
  const int lane = tid & 63;
  const unsigned* m32 = (const unsigned*)mask;

  // --- scalar-load layout detect (uniform address -> s_load) ---
  unsigned acc = 0;
#pragma unroll
  for (int j = 0; j < 16; ++j) acc |= m32[(size_t)b * 512 + j];
  const bool is_byte = (acc != 0u) && (acc != 1u) && (acc != 0x3F800000u);

  // --- register loads of rand + mask for key build ---
  float rv[4]; unsigned mw[4];
#pragma unroll
  for (int k = 0; k < 4; ++k) {
    const int l = tid + 512 * k;
    rv[k] = rnd[(size_t)b * LL + l];
    mw[k] = is_byte ? m32[(size_t)b * 512 + (l >> 2)]
                    : m32[(size_t)b * LL + l];
  }

  const float* const xs = x + (size_t)b * CC * LL;
  const float* const vs = v + (size_t)b * CVV * LL;
  float* const xd = xo + (size_t)b * CC * LL;
  float* const vd = vo + (size_t)b * CVV * LL;

#define SRCROW(rr) ((rr) < CC ? xs + (size_t)(rr) * LL \
                              : vs + (size_t)((rr) - CC) * LL)
#define DSTROW(rr) ((rr) < CC ? xd + (size_t)(rr) * LL \
                              : vd + (size_t)((rr) - CC) * LL)

  // --- ASM prefetch rows 0..15 into named regs (cannot be sunk) ---
  float4 A0, A1, A2, A3, A4, A5, A6, A7;
  float4 A8, A9, A10, A11, A12, A13, A14, A15;
  ALOAD(A0,  (const float4*)SRCROW(0)  + tid);
  ALOAD(A1,  (const float4*)SRCROW(1)  + tid);
  ALOAD(A2,  (const float4*)SRCROW(2)  + tid);
  ALOAD(A3,  (const float4*)SRCROW(3)  + tid);
  ALOAD(A4,  (const float4*)SRCROW(4)  + tid);
  ALOAD(A5,  (const float4*)SRCROW(5)  + tid);
  ALOAD(A6,  (const float4*)SRCROW(6)  + tid);
  ALOAD(A7,  (const float4*)SRCROW(7)  + tid);
  ALOAD(A8,  (const float4*)SRCROW(8)  + tid);
  ALOAD(A9,  (const float4*)SRCROW(9)  + tid);
  ALOAD(A10, (const float4*)SRCROW(10) + tid);
  ALOAD(A11, (const float4*)SRCROW(11) + tid);
  ALOAD(A12, (const float4*)SRCROW(12) + tid);
  ALOAD(A13, (const float4*)SRCROW(13) + tid);
  ALOAD(A14, (const float4*)SRCROW(14) + tid);
  ALOAD(A15, (const float4*)SRCROW(15) + tid);

  // --- build composite keys ---
  const int sh8 = 8 * (tid & 3);
  int local = 0;
#pragma unroll
  for (int k = 0; k < 4; ++k) {
    const int l = tid + 512 * k;
    const bool m = is_byte ? (((mw[k] >> sh8) & 0xFFu) != 0u) : (mw[k] != 0u);
    float rf = m ? -1.0f : rv[k];
    unsigned u = __float_as_uint(rf);
    u = (u & 0x80000000u) ? ~u : (u | 0x80000000u);  // order-preserving map
    sh.key[KIDX(l)] = ((unsigned long long)u << 32) | (unsigned)(LL - 1 - l);
    local += m ? 1 : 0;
  }
#pragma unroll
  for (int off = 32; off > 0; off >>= 1) local += __shfl_down(local, off, 64);
  if (lane == 0) wcnt[w] = local;
  SBAR_LDS();

  // --- bitonic sort, descending; wave w owns key[w*256 .. w*256+255] ---
  for (int size = 2; size <= 256; size <<= 1) {
    for (int stride = size >> 1; stride > 0; stride >>= 1) {
#pragma unroll
      for (int pp = 0; pp < 2; ++pp) {
        int p = w * 128 + pp * 64 + lane;
        int i = ((p & ~(stride - 1)) << 1) | (p & (stride - 1));
        ce_desc(sh.key, i, i + stride, (i & size) == 0);
      }
      __builtin_amdgcn_wave_barrier();
    }
  }
  SBAR_LDS();
  for (int size = 512; size <= 2048; size <<= 1) {
    for (int stride = size >> 1; stride >= 256; stride >>= 1) {
      for (int t = tid; t < LL / 2; t += 512) {
        int i = ((t & ~(stride - 1)) << 1) | (t & (stride - 1));
        ce_desc(sh.key, i, i + stride, (i & size) == 0);
      }
      SBAR_LDS();
    }
    for (int stride = 128; stride > 0; stride >>= 1) {
#pragma unroll
      for (int pp = 0; pp < 2; ++pp) {
        int p = w * 128 + pp * 64 + lane;
        int i = ((p & ~(stride - 1)) << 1) | (p & (stride - 1));
        ce_desc(sh.key, i, i + stride, (i & size) == 0);
      }
      __builtin_amdgcn_wave_barrier();
    }
    SBAR_LDS();
  }

  // --- extract perm into registers; write mask_t ---
  const int cnt = wcnt[0] + wcnt[1] + wcnt[2] + wcnt[3] +
                  wcnt[4] + wcnt[5] + wcnt[6] + wcnt[7];
  const int maxlen = cnt > 1 ? cnt : 1;              // jnp.maximum(count, 1)
  const unsigned ordNeg1 = ~__float_as_uint(-1.0f);  // ord(-1.0)
  int sv[4]; float mf[4];
#pragma unroll
  for (int k = 0; k < 4; ++k) {
    const int j = tid * 4 + k;
    unsigned long long k2 = sh.key[KIDX(j)];
    int idx = (LL - 1) - (int)(unsigned)(k2 & 0xFFFFFFFFull);
    bool masked = ((unsigned)(k2 >> 32)) == ordNeg1;
    bool keep = j < maxlen;
    sv[k] = idx | (keep ? (1 << 12) : 0);
    mf[k] = (keep && masked) ? 1.0f : 0.0f;
  }
  const int4 s = make_int4(sv[0], sv[1], sv[2], sv[3]);
  ((float4*)(mo + (size_t)b * LL))[tid] =
      make_float4(mf[0], mf[1], mf[2], mf[3]);   // S_mask in the vmem queue
  SBAR_LDS();  // all key[] reads done before ring slots get written

#define GATHER1(buf, dst) do { \
    float4 o; \
    o.x = (s.x & (1 << 12)) ? (buf)[s.x & 0x7FF] : 0.0f; \
    o.y = (s.y & (1 << 12)) ? (buf)[s.y & 0x7FF] : 0.0f; \
    o.z = (s.z & (1 << 12)) ? (buf)[s.z & 0x7FF] : 0.0f; \
    o.w = (s.w & (1 << 12)) ? (buf)[s.w & 0x7FF] : 0.0f; \
    ((float4*)(dst))[tid] = o; \
  } while (0)

  // Quad: ds_write 4 rows from named regs, ONE barrier, reload regs with
  // rows +16 (plain loads, compiler-tracked), gather+store the 4 rows.
  // Ring safety: quad qq writes slots last gathered at quad qq-2, separated
  // by barrier qq-1.
#define QUAD(qq, RA, RB, RC, RD) do { \
    constexpr int r0 = 4 * (qq); \
    constexpr int s0 = (4 * (qq)) & 7; \
    ((float4*)&sh.ring[s0 + 0][0])[tid] = RA; \
    ((float4*)&sh.ring[s0 + 1][0])[tid] = RB; \
    ((float4*)&sh.ring[s0 + 2][0])[tid] = RC; \
    ((float4*)&sh.ring[s0 + 3][0])[tid] = RD; \
    SBAR_LDS(); \
    if constexpr (r0 + 16 < NR) RA = ((const float4*)SRCROW(r0 + 16))[tid]; \
    if constexpr (r0 + 17 < NR) RB = ((const float4*)SRCROW(r0 + 17))[tid]; \
    if constexpr (r0 + 18 < NR) RC = ((const float4*)SRCROW(r0 + 18))[tid]; \
    if constexpr (r0 + 19 < NR) RD = ((const float4*)SRCROW(r0 + 19))[tid]; \
    GATHER1(&sh.ring[s0 + 0][0], DSTROW(r0 + 0)); \
    GATHER1(&sh.ring[s0 + 1][0], DSTROW(r0 + 1)); \
    GATHER1(&sh.ring[s0 + 2][0], DSTROW(r0 + 2)); \
    GATHER1(&sh.ring[s0 + 3][0], DSTROW(r0 + 3)); \
  } while (0)

  // Quads 0-3 consume asm-loaded regs: manual conservative waits.
  // Known-newer at each point: prefetch loads not yet needed + S_mask.
  WAITV(13); QUAD(0,  A0,  A1,  A2,  A3);   // need L0-3;  newer>=12L+1S
  WAITV(9);  QUAD(1,  A4,  A5,  A6,  A7);   // need L4-7;  newer>=8L+1S
  WAITV(5);  QUAD(2,  A8,  A9,  A10, A11);  // need L8-11; newer>=4L+1S
  WAITV(1);  QUAD(3,  A12, A13, A14, A15);  // need L12-15; newer>=1S
  QUAD(4,  A0,  A1,  A2,  A3);
  QUAD(5,  A4,  A5,  A6,  A7);
  QUAD(6,  A8,  A9,  A10, A11);
  QUAD(7,  A12, A13, A14, A15);
  QUAD(8,  A0,  A1,  A2,  A3);
  QUAD(9,  A4,  A5,  A6,  A7);
  QUAD(10, A8,  A9,  A10, A11);
  QUAD(11, A12, A13, A14, A15);
  QUAD(12, A0,  A1,  A2,  A3);
  QUAD(13, A4,  A5,  A6,  A7);
  QUAD(14, A8,  A9,  A10, A11);
  QUAD(15, A12, A13, A14, A15);
  QUAD(16, A0,  A1,  A2,  A3);
#undef QUAD
#undef GATHER1
#undef SRCROW
#undef DSTROW
}

extern "C" void kernel_launch(void* const* d_in, const int* in_sizes, int n_in,
                              void* d_out, int out_size, void* d_ws, size_t ws_size,
                              hipStream_t stream) {
  const float* x    = (const float*)d_in[0];
  const float* v    = (const float*)d_in[1];
  const void*  mask = d_in[2];
  const float* rnd  = (const float*)d_in[3];

  float* xo = (float*)d_out;                  // B*C*L
  float* vo = xo + (size_t)BB * CC * LL;      // B*CV*L
  float* mo = vo + (size_t)BB * CVV * LL;     // B*1*L

  trimmer_kernel<<<BB, 512, 0, stream>>>(x, v, mask, rnd, xo, vo, mo);
}

// Round 17
// 59.683 us; speedup vs baseline: 1.1333x; 1.1190x over previous
//
#include <hip/hip_runtime.h>
#include <stdint.h>

typedef unsigned long long ull;

#define BB 256
#define CC 64
#define CVV 4
#define LL 2048
#define NR (CC + CVV)   // 68 rows per block (= per batch)

// LDS-only barrier: orders ds ops across waves WITHOUT draining vmcnt.
#define SBAR_LDS() do { \
    asm volatile("s_waitcnt lgkmcnt(0)" ::: "memory"); \
    __builtin_amdgcn_s_barrier(); \
    __builtin_amdgcn_sched_barrier(0); \
  } while (0)

// Intra-thread compare-exchange of a pair: lower-index element A keeps max
// iff the enclosing bitonic block is descending.
#define CEP(A, B, descblk) do { \
    ull _lo = (A < B) ? A : B; \
    ull _hi = (A < B) ? B : A; \
    A = (descblk) ? _hi : _lo; \
    B = (descblk) ? _lo : _hi; \
  } while (0)

// Shuffle compare-exchange: partner via lane XOR; keep max iff keepmax.
#define CES(E, s4, keepmax) do { \
    ull _p = __shfl_xor(E, (s4), 64); \
    E = (keepmax) ? ((E >= _p) ? E : _p) : ((E <= _p) ? E : _p); \
  } while (0)

__device__ __forceinline__ ull mkkey(bool m, float r, int i) {
  float rf = m ? -1.0f : r;
  unsigned u = __float_as_uint(rf);
  u = (u & 0x80000000u) ? ~u : (u | 0x80000000u);  // order-preserving map
  return ((ull)u << 32) | (unsigned)(LL - 1 - i);
}

// ---------------------------------------------------------------------------
// One block per batch (256 blocks = 1/CU, 512 threads = 8 waves).
// Phase 1: REGISTER/SHUFFLE bitonic argsort (stable descending on composite
//   ord(rand_f)<<32 | (L-1-idx)). Thread t owns elements 4t..4t+3 in regs
//   e0..e3. Strides 1,2: intra-thread CEP. Strides 4..128: __shfl_xor CES
//   (conflict-free, barrier-free). Strides 256/512/1024 (6 of 66 substages):
//   LDS exchange at padded base 5t (banks 10t%32 -> conflict-free), write /
//   SBAR / read XOR-partner / SBAR. Sort LDS traffic: 3.2 MB -> 0.2 MB;
//   barriers: ~20 -> 12; sorted keys END in the registers the extraction
//   needs (positions 4tid..4tid+3) - no extraction LDS read.
// Phase 2: R14's register-staged quad gather verbatim: 16 named float4 regs
//   (rows 0..15 prefetched before the sort), 8-slot LDS ring (64 KB), four
//   rows per LDS-only barrier, reload distance 16, compiler-tracked vmcnt.
// ---------------------------------------------------------------------------
__global__ __launch_bounds__(512) void trimmer_kernel(
    const float* __restrict__ x, const float* __restrict__ v,
    const void* __restrict__ mask, const float* __restrict__ rnd,
    float* __restrict__ xo, float* __restrict__ vo, float* __restrict__ mo) {
  __shared__ union {
    ull key[2560];       // padded exchange buffer (20 KB), slots 0..2 region
    float ring[8][LL];   // 8 x 8 KB = 64 KB
  } sh;
  __shared__ int wcnt[8];

  const int b = blockIdx.x;
  const int tid = threadIdx.x;
  const int w = tid >> 6;
  const int lane = tid & 63;
  const unsigned* m32 = (const unsigned*)mask;

  // --- scalar-load layout detect (uniform address -> s_load) ---
  unsigned acc = 0;
#pragma unroll
  for (int j = 0; j < 16; ++j) acc |= m32[(size_t)b * 512 + j];
  const bool is_byte = (acc != 0u) && (acc != 1u) && (acc != 0x3F800000u);

  // --- rand + mask for this thread's 4 elements (issued before prefetch) ---
  const float4 rv4 = ((const float4*)(rnd + (size_t)b * LL))[tid];
  unsigned mq0, mq1, mq2, mq3;
  if (is_byte) {
    unsigned word = m32[(size_t)b * 512 + tid];   // bytes 4t..4t+3
    mq0 = word & 0xFFu; mq1 = (word >> 8) & 0xFFu;
    mq2 = (word >> 16) & 0xFFu; mq3 = (word >> 24) & 0xFFu;
  } else {
    int4 t4 = ((const int4*)m32)[(size_t)b * 512 + tid];  // ints 4t..4t+3
    mq0 = t4.x; mq1 = t4.y; mq2 = t4.z; mq3 = t4.w;
  }

  const float* const xs = x + (size_t)b * CC * LL;
  const float* const vs = v + (size_t)b * CVV * LL;
  float* const xd = xo + (size_t)b * CC * LL;
  float* const vd = vo + (size_t)b * CVV * LL;

#define SRCROW(rr) ((rr) < CC ? xs + (size_t)(rr) * LL \
                              : vs + (size_t)((rr) - CC) * LL)
#define DSTROW(rr) ((rr) < CC ? xd + (size_t)(rr) * LL \
                              : vd + (size_t)((rr) - CC) * LL)

  // --- prefetch rows 0..15 into named registers ---
  float4 A0  = ((const float4*)SRCROW(0))[tid];
  float4 A1  = ((const float4*)SRCROW(1))[tid];
  float4 A2  = ((const float4*)SRCROW(2))[tid];
  float4 A3  = ((const float4*)SRCROW(3))[tid];
  float4 A4  = ((const float4*)SRCROW(4))[tid];
  float4 A5  = ((const float4*)SRCROW(5))[tid];
  float4 A6  = ((const float4*)SRCROW(6))[tid];
  float4 A7  = ((const float4*)SRCROW(7))[tid];
  float4 A8  = ((const float4*)SRCROW(8))[tid];
  float4 A9  = ((const float4*)SRCROW(9))[tid];
  float4 A10 = ((const float4*)SRCROW(10))[tid];
  float4 A11 = ((const float4*)SRCROW(11))[tid];
  float4 A12 = ((const float4*)SRCROW(12))[tid];
  float4 A13 = ((const float4*)SRCROW(13))[tid];
  float4 A14 = ((const float4*)SRCROW(14))[tid];
  float4 A15 = ((const float4*)SRCROW(15))[tid];

  // --- build keys in registers; count masked ---
  ull e0 = mkkey(mq0 != 0u, rv4.x, 4 * tid + 0);
  ull e1 = mkkey(mq1 != 0u, rv4.y, 4 * tid + 1);
  ull e2 = mkkey(mq2 != 0u, rv4.z, 4 * tid + 2);
  ull e3 = mkkey(mq3 != 0u, rv4.w, 4 * tid + 3);
  int local = (mq0 != 0u) + (mq1 != 0u) + (mq2 != 0u) + (mq3 != 0u);
#pragma unroll
  for (int off = 32; off > 0; off >>= 1) local += __shfl_down(local, off, 64);
  if (lane == 0) wcnt[w] = local;

  // ================= bitonic sort, descending, in registers ================
  // size 2: pair (e0,e1) desc, (e2,e3) asc  [i&2: 4t->0, 4t+2->2]
  CEP(e0, e1, true);
  CEP(e2, e3, false);
  // size 4: d = (t&1)==0; strides 2,1
  {
    const bool d = (tid & 1) == 0;
    CEP(e0, e2, d); CEP(e1, e3, d);
    CEP(e0, e1, d); CEP(e2, e3, d);
  }
  // sizes 8..256: strides 4..128 via shfl_xor, then 2,1 intra
  for (int size = 8; size <= 256; size <<= 1) {
    const bool d = (tid & (size >> 2)) == 0;
    for (int s4 = size >> 3; s4 >= 1; s4 >>= 1) {   // s4 = stride/4
      const bool keepmax = (d == ((tid & s4) == 0));
      CES(e0, s4, keepmax); CES(e1, s4, keepmax);
      CES(e2, s4, keepmax); CES(e3, s4, keepmax);
    }
    CEP(e0, e2, d); CEP(e1, e3, d);
    CEP(e0, e1, d); CEP(e2, e3, d);
  }
  // sizes 512..2048: strides >=256 via padded-LDS exchange, rest in regs
  for (int size = 512; size <= 2048; size <<= 1) {
    const bool d = (tid & (size >> 2)) == 0;
    for (int s4 = size >> 3; s4 >= 64; s4 >>= 1) {  // stride = 4*s4 >= 256
      ull* kp = &sh.key[5 * tid];                   // padded base: bank 10t%32
      kp[0] = e0; kp[1] = e1; kp[2] = e2; kp[3] = e3;
      SBAR_LDS();
      const ull* pp = &sh.key[5 * (tid ^ s4)];
      ull p0 = pp[0], p1 = pp[1], p2 = pp[2], p3 = pp[3];
      const bool keepmax = (d == ((tid & s4) == 0));
      e0 = keepmax ? ((e0 >= p0) ? e0 : p0) : ((e0 <= p0) ? e0 : p0);
      e1 = keepmax ? ((e1 >= p1) ? e1 : p1) : ((e1 <= p1) ? e1 : p1);
      e2 = keepmax ? ((e2 >= p2) ? e2 : p2) : ((e2 <= p2) ? e2 : p2);
      e3 = keepmax ? ((e3 >= p3) ? e3 : p3) : ((e3 <= p3) ? e3 : p3);
      SBAR_LDS();   // partner reads done before anyone's next write
    }
    for (int s4 = 32; s4 >= 1; s4 >>= 1) {          // strides 128..4
      const bool keepmax = (d == ((tid & s4) == 0));
      CES(e0, s4, keepmax); CES(e1, s4, keepmax);
      CES(e2, s4, keepmax); CES(e3, s4, keepmax);
    }
    CEP(e0, e2, d); CEP(e1, e3, d);
    CEP(e0, e1, d); CEP(e2, e3, d);
  }
  // ========================================================================
  // Sorted keys for output positions 4*tid..4*tid+3 are now e0..e3 (regs).

  const int cnt = wcnt[0] + wcnt[1] + wcnt[2] + wcnt[3] +
                  wcnt[4] + wcnt[5] + wcnt[6] + wcnt[7];
  const int maxlen = cnt > 1 ? cnt : 1;              // jnp.maximum(count, 1)
  const unsigned ordNeg1 = ~__float_as_uint(-1.0f);  // ord(-1.0)

#define EXT(E, k, SV, MF) do { \
    const int _j = 4 * tid + (k); \
    int _idx = (LL - 1) - (int)(unsigned)((E) & 0xFFFFFFFFull); \
    bool _masked = ((unsigned)((E) >> 32)) == ordNeg1; \
    bool _keep = _j < maxlen; \
    SV = _idx | (_keep ? (1 << 12) : 0); \
    MF = (_keep && _masked) ? 1.0f : 0.0f; \
  } while (0)
  int sv0, sv1, sv2, sv3; float mf0, mf1, mf2, mf3;
  EXT(e0, 0, sv0, mf0); EXT(e1, 1, sv1, mf1);
  EXT(e2, 2, sv2, mf2); EXT(e3, 3, sv3, mf3);
#undef EXT
  const int4 s = make_int4(sv0, sv1, sv2, sv3);
  ((float4*)(mo + (size_t)b * LL))[tid] = make_float4(mf0, mf1, mf2, mf3);
  // No extra barrier needed: the last key[] read was followed by SBAR_LDS
  // inside the exchange loop; everything since is register-only.

#define GATHER1(buf, dst) do { \
    float4 o; \
    o.x = (s.x & (1 << 12)) ? (buf)[s.x & 0x7FF] : 0.0f; \
    o.y = (s.y & (1 << 12)) ? (buf)[s.y & 0x7FF] : 0.0f; \
    o.z = (s.z & (1 << 12)) ? (buf)[s.z & 0x7FF] : 0.0f; \
    o.w = (s.w & (1 << 12)) ? (buf)[s.w & 0x7FF] : 0.0f; \
    ((float4*)(dst))[tid] = o; \
  } while (0)

  // Quad: ds_write 4 rows from named regs, ONE barrier, reload regs with
  // rows +16 (compiler-tracked vmcnt), gather+store the 4 rows.
  // Ring safety: quad qq writes slots last gathered at quad qq-2, separated
  // by barrier qq-1.
#define QUAD(qq, RA, RB, RC, RD) do { \
    constexpr int r0 = 4 * (qq); \
    constexpr int s0 = (4 * (qq)) & 7; \
    ((float4*)&sh.ring[s0 + 0][0])[tid] = RA; \
    ((float4*)&sh.ring[s0 + 1][0])[tid] = RB; \
    ((float4*)&sh.ring[s0 + 2][0])[tid] = RC; \
    ((float4*)&sh.ring[s0 + 3][0])[tid] = RD; \
    SBAR_LDS(); \
    if constexpr (r0 + 16 < NR) RA = ((const float4*)SRCROW(r0 + 16))[tid]; \
    if constexpr (r0 + 17 < NR) RB = ((const float4*)SRCROW(r0 + 17))[tid]; \
    if constexpr (r0 + 18 < NR) RC = ((const float4*)SRCROW(r0 + 18))[tid]; \
    if constexpr (r0 + 19 < NR) RD = ((const float4*)SRCROW(r0 + 19))[tid]; \
    GATHER1(&sh.ring[s0 + 0][0], DSTROW(r0 + 0)); \
    GATHER1(&sh.ring[s0 + 1][0], DSTROW(r0 + 1)); \
    GATHER1(&sh.ring[s0 + 2][0], DSTROW(r0 + 2)); \
    GATHER1(&sh.ring[s0 + 3][0], DSTROW(r0 + 3)); \
  } while (0)

  QUAD(0,  A0,  A1,  A2,  A3);
  QUAD(1,  A4,  A5,  A6,  A7);
  QUAD(2,  A8,  A9,  A10, A11);
  QUAD(3,  A12, A13, A14, A15);
  QUAD(4,  A0,  A1,  A2,  A3);
  QUAD(5,  A4,  A5,  A6,  A7);
  QUAD(6,  A8,  A9,  A10, A11);
  QUAD(7,  A12, A13, A14, A15);
  QUAD(8,  A0,  A1,  A2,  A3);
  QUAD(9,  A4,  A5,  A6,  A7);
  QUAD(10, A8,  A9,  A10, A11);
  QUAD(11, A12, A13, A14, A15);
  QUAD(12, A0,  A1,  A2,  A3);
  QUAD(13, A4,  A5,  A6,  A7);
  QUAD(14, A8,  A9,  A10, A11);
  QUAD(15, A12, A13, A14, A15);
  QUAD(16, A0,  A1,  A2,  A3);
#undef QUAD
#undef GATHER1
#undef SRCROW
#undef DSTROW
}

extern "C" void kernel_launch(void* const* d_in, const int* in_sizes, int n_in,
                              void* d_out, int out_size, void* d_ws, size_t ws_size,
                              hipStream_t stream) {
  const float* x    = (const float*)d_in[0];
  const float* v    = (const float*)d_in[1];
  const void*  mask = d_in[2];
  const float* rnd  = (const float*)d_in[3];

  float* xo = (float*)d_out;                  // B*C*L
  float* vo = xo + (size_t)BB * CC * LL;      // B*CV*L
  float* mo = vo + (size_t)BB * CVV * LL;     // B*1*L

  trimmer_kernel<<<BB, 512, 0, stream>>>(x, v, mask, rnd, xo, vo, mo);
}

// Round 18
// 58.325 us; speedup vs baseline: 1.1597x; 1.0233x over previous
//
#include <hip/hip_runtime.h>
#include <stdint.h>

typedef unsigned long long ull;

#define BB 256
#define CC 64
#define CVV 4
#define LL 2048
#define NRB 34   // rows per block (68 / 2 blocks per batch)

// LDS-only barrier: orders ds ops across waves WITHOUT draining vmcnt.
#define SBAR_LDS() do { \
    asm volatile("s_waitcnt lgkmcnt(0)" ::: "memory"); \
    __builtin_amdgcn_s_barrier(); \
    __builtin_amdgcn_sched_barrier(0); \
  } while (0)

// Intra-thread compare-exchange of a pair.
#define CEP(A, B, descblk) do { \
    ull _lo = (A < B) ? A : B; \
    ull _hi = (A < B) ? B : A; \
    A = (descblk) ? _hi : _lo; \
    B = (descblk) ? _lo : _hi; \
  } while (0)

// Shuffle compare-exchange: partner via lane XOR; keep max iff keepmax.
#define CES(E, s4, keepmax) do { \
    ull _p = __shfl_xor(E, (s4), 64); \
    E = (keepmax) ? ((E >= _p) ? E : _p) : ((E <= _p) ? E : _p); \
  } while (0)

__device__ __forceinline__ ull mkkey(bool m, float r, int i) {
  float rf = m ? -1.0f : r;
  unsigned u = __float_as_uint(rf);
  u = (u & 0x80000000u) ? ~u : (u | 0x80000000u);  // order-preserving map
  return ((ull)u << 32) | (unsigned)(LL - 1 - i);
}

// ---------------------------------------------------------------------------
// Grid 512 = 2 blocks per batch (b = blockIdx>>1, half g = blockIdx&1),
// 512 threads each -> 2 blocks/CU, 16 waves/CU during the gather.
// Phase 1 (per block, duplicated across the batch's 2 blocks - shuffle sort
//   is VALU-bound and runs concurrently on different SIMDs): register/shuffle
//   bitonic argsort, stable descending on ord(rand_f)<<32 | (L-1-idx).
//   Thread t owns elements 4t..4t+3 in regs; strides 1,2 intra-thread;
//   4..128 via __shfl_xor; 256/512/1024 via padded-LDS exchange (6 of 66
//   substages, 12 barriers). Sorted keys end in the extraction registers.
// Phase 2: register-staged quad gather of this block's 34 rows: 16 named
//   float4 regs (rows g*34..+15 prefetched pre-sort), 8-slot LDS ring,
//   4 rows per LDS-only barrier, reload distance 16. 8 quads + epilogue
//   pair = 10 barrier events; 2 independent domains per CU.
// ---------------------------------------------------------------------------
__global__ __launch_bounds__(512) void trimmer_kernel(
    const float* __restrict__ x, const float* __restrict__ v,
    const void* __restrict__ mask, const float* __restrict__ rnd,
    float* __restrict__ xo, float* __restrict__ vo, float* __restrict__ mo) {
  __shared__ union {
    ull key[2560];       // padded exchange buffer (20 KB)
    float ring[8][LL];   // 8 x 8 KB = 64 KB
  } sh;
  __shared__ int wcnt[8];

  const int b = blockIdx.x >> 1;
  const int g = blockIdx.x & 1;
  const int tid = threadIdx.x;
  const int w = tid >> 6;
  const int lane = tid & 63;
  const unsigned* m32 = (const unsigned*)mask;

  // --- scalar-load layout detect (uniform address -> s_load) ---
  unsigned acc = 0;
#pragma unroll
  for (int j = 0; j < 16; ++j) acc |= m32[(size_t)b * 512 + j];
  const bool is_byte = (acc != 0u) && (acc != 1u) && (acc != 0x3F800000u);

  // --- rand + mask for this thread's 4 elements ---
  const float4 rv4 = ((const float4*)(rnd + (size_t)b * LL))[tid];
  unsigned mq0, mq1, mq2, mq3;
  if (is_byte) {
    unsigned word = m32[(size_t)b * 512 + tid];   // bytes 4t..4t+3
    mq0 = word & 0xFFu; mq1 = (word >> 8) & 0xFFu;
    mq2 = (word >> 16) & 0xFFu; mq3 = (word >> 24) & 0xFFu;
  } else {
    int4 t4 = ((const int4*)m32)[(size_t)b * 512 + tid];  // ints 4t..4t+3
    mq0 = t4.x; mq1 = t4.y; mq2 = t4.z; mq3 = t4.w;
  }

  const float* const xs = x + (size_t)b * CC * LL;
  const float* const vs = v + (size_t)b * CVV * LL;
  float* const xd = xo + (size_t)b * CC * LL;
  float* const vd = vo + (size_t)b * CVV * LL;

#define SRCROW(rr) ((g * NRB + (rr)) < CC \
    ? xs + (size_t)(g * NRB + (rr)) * LL \
    : vs + (size_t)(g * NRB + (rr) - CC) * LL)
#define DSTROW(rr) ((g * NRB + (rr)) < CC \
    ? xd + (size_t)(g * NRB + (rr)) * LL \
    : vd + (size_t)(g * NRB + (rr) - CC) * LL)

  // --- prefetch rows 0..15 (of this block's 34) into named registers ---
  float4 A0  = ((const float4*)SRCROW(0))[tid];
  float4 A1  = ((const float4*)SRCROW(1))[tid];
  float4 A2  = ((const float4*)SRCROW(2))[tid];
  float4 A3  = ((const float4*)SRCROW(3))[tid];
  float4 A4  = ((const float4*)SRCROW(4))[tid];
  float4 A5  = ((const float4*)SRCROW(5))[tid];
  float4 A6  = ((const float4*)SRCROW(6))[tid];
  float4 A7  = ((const float4*)SRCROW(7))[tid];
  float4 A8  = ((const float4*)SRCROW(8))[tid];
  float4 A9  = ((const float4*)SRCROW(9))[tid];
  float4 A10 = ((const float4*)SRCROW(10))[tid];
  float4 A11 = ((const float4*)SRCROW(11))[tid];
  float4 A12 = ((const float4*)SRCROW(12))[tid];
  float4 A13 = ((const float4*)SRCROW(13))[tid];
  float4 A14 = ((const float4*)SRCROW(14))[tid];
  float4 A15 = ((const float4*)SRCROW(15))[tid];

  // --- build keys in registers; count masked ---
  ull e0 = mkkey(mq0 != 0u, rv4.x, 4 * tid + 0);
  ull e1 = mkkey(mq1 != 0u, rv4.y, 4 * tid + 1);
  ull e2 = mkkey(mq2 != 0u, rv4.z, 4 * tid + 2);
  ull e3 = mkkey(mq3 != 0u, rv4.w, 4 * tid + 3);
  int local = (mq0 != 0u) + (mq1 != 0u) + (mq2 != 0u) + (mq3 != 0u);
#pragma unroll
  for (int off = 32; off > 0; off >>= 1) local += __shfl_down(local, off, 64);
  if (lane == 0) wcnt[w] = local;

  // ================= bitonic sort, descending, in registers ================
  CEP(e0, e1, true);
  CEP(e2, e3, false);
  {
    const bool d = (tid & 1) == 0;
    CEP(e0, e2, d); CEP(e1, e3, d);
    CEP(e0, e1, d); CEP(e2, e3, d);
  }
  for (int size = 8; size <= 256; size <<= 1) {
    const bool d = (tid & (size >> 2)) == 0;
    for (int s4 = size >> 3; s4 >= 1; s4 >>= 1) {
      const bool keepmax = (d == ((tid & s4) == 0));
      CES(e0, s4, keepmax); CES(e1, s4, keepmax);
      CES(e2, s4, keepmax); CES(e3, s4, keepmax);
    }
    CEP(e0, e2, d); CEP(e1, e3, d);
    CEP(e0, e1, d); CEP(e2, e3, d);
  }
  for (int size = 512; size <= 2048; size <<= 1) {
    const bool d = (tid & (size >> 2)) == 0;
    for (int s4 = size >> 3; s4 >= 64; s4 >>= 1) {  // stride = 4*s4 >= 256
      ull* kp = &sh.key[5 * tid];                   // padded: bank 10t%32
      kp[0] = e0; kp[1] = e1; kp[2] = e2; kp[3] = e3;
      SBAR_LDS();
      const ull* pp = &sh.key[5 * (tid ^ s4)];
      ull p0 = pp[0], p1 = pp[1], p2 = pp[2], p3 = pp[3];
      const bool keepmax = (d == ((tid & s4) == 0));
      e0 = keepmax ? ((e0 >= p0) ? e0 : p0) : ((e0 <= p0) ? e0 : p0);
      e1 = keepmax ? ((e1 >= p1) ? e1 : p1) : ((e1 <= p1) ? e1 : p1);
      e2 = keepmax ? ((e2 >= p2) ? e2 : p2) : ((e2 <= p2) ? e2 : p2);
      e3 = keepmax ? ((e3 >= p3) ? e3 : p3) : ((e3 <= p3) ? e3 : p3);
      SBAR_LDS();   // partner reads done before anyone's next write
    }
    for (int s4 = 32; s4 >= 1; s4 >>= 1) {
      const bool keepmax = (d == ((tid & s4) == 0));
      CES(e0, s4, keepmax); CES(e1, s4, keepmax);
      CES(e2, s4, keepmax); CES(e3, s4, keepmax);
    }
    CEP(e0, e2, d); CEP(e1, e3, d);
    CEP(e0, e1, d); CEP(e2, e3, d);
  }
  // ========================================================================
  // Sorted keys for output positions 4*tid..4*tid+3 are now e0..e3.

  const int cnt = wcnt[0] + wcnt[1] + wcnt[2] + wcnt[3] +
                  wcnt[4] + wcnt[5] + wcnt[6] + wcnt[7];
  const int maxlen = cnt > 1 ? cnt : 1;              // jnp.maximum(count, 1)
  const unsigned ordNeg1 = ~__float_as_uint(-1.0f);  // ord(-1.0)

#define EXT(E, k, SV, MF) do { \
    const int _j = 4 * tid + (k); \
    int _idx = (LL - 1) - (int)(unsigned)((E) & 0xFFFFFFFFull); \
    bool _masked = ((unsigned)((E) >> 32)) == ordNeg1; \
    bool _keep = _j < maxlen; \
    SV = _idx | (_keep ? (1 << 12) : 0); \
    MF = (_keep && _masked) ? 1.0f : 0.0f; \
  } while (0)
  int sv0, sv1, sv2, sv3; float mf0, mf1, mf2, mf3;
  EXT(e0, 0, sv0, mf0); EXT(e1, 1, sv1, mf1);
  EXT(e2, 2, sv2, mf2); EXT(e3, 3, sv3, mf3);
#undef EXT
  const int4 s = make_int4(sv0, sv1, sv2, sv3);
  if (g == 0)
    ((float4*)(mo + (size_t)b * LL))[tid] = make_float4(mf0, mf1, mf2, mf3);
  // Last key[] read was followed by SBAR_LDS inside the exchange loop.

#define GATHER1(buf, dst) do { \
    float4 o; \
    o.x = (s.x & (1 << 12)) ? (buf)[s.x & 0x7FF] : 0.0f; \
    o.y = (s.y & (1 << 12)) ? (buf)[s.y & 0x7FF] : 0.0f; \
    o.z = (s.z & (1 << 12)) ? (buf)[s.z & 0x7FF] : 0.0f; \
    o.w = (s.w & (1 << 12)) ? (buf)[s.w & 0x7FF] : 0.0f; \
    ((float4*)(dst))[tid] = o; \
  } while (0)

  // Quad: ds_write 4 rows, ONE barrier, reload regs +16, gather 4 rows.
  // Ring safety: quad qq writes slots last gathered at quad qq-2, separated
  // by barrier qq-1.
#define QUAD(qq, RA, RB, RC, RD) do { \
    constexpr int r0 = 4 * (qq); \
    constexpr int s0 = (4 * (qq)) & 7; \
    ((float4*)&sh.ring[s0 + 0][0])[tid] = RA; \
    ((float4*)&sh.ring[s0 + 1][0])[tid] = RB; \
    ((float4*)&sh.ring[s0 + 2][0])[tid] = RC; \
    ((float4*)&sh.ring[s0 + 3][0])[tid] = RD; \
    SBAR_LDS(); \
    if constexpr (r0 + 16 < NRB) RA = ((const float4*)SRCROW(r0 + 16))[tid]; \
    if constexpr (r0 + 17 < NRB) RB = ((const float4*)SRCROW(r0 + 17))[tid]; \
    if constexpr (r0 + 18 < NRB) RC = ((const float4*)SRCROW(r0 + 18))[tid]; \
    if constexpr (r0 + 19 < NRB) RD = ((const float4*)SRCROW(r0 + 19))[tid]; \
    GATHER1(&sh.ring[s0 + 0][0], DSTROW(r0 + 0)); \
    GATHER1(&sh.ring[s0 + 1][0], DSTROW(r0 + 1)); \
    GATHER1(&sh.ring[s0 + 2][0], DSTROW(r0 + 2)); \
    GATHER1(&sh.ring[s0 + 3][0], DSTROW(r0 + 3)); \
  } while (0)

  QUAD(0, A0,  A1,  A2,  A3);    // rows 0-3;   reload 16-19
  QUAD(1, A4,  A5,  A6,  A7);    // rows 4-7;   reload 20-23
  QUAD(2, A8,  A9,  A10, A11);   // rows 8-11;  reload 24-27
  QUAD(3, A12, A13, A14, A15);   // rows 12-15; reload 28-31
  QUAD(4, A0,  A1,  A2,  A3);    // rows 16-19; reload 32,33 (guarded)
  QUAD(5, A4,  A5,  A6,  A7);    // rows 20-23
  QUAD(6, A8,  A9,  A10, A11);   // rows 24-27
  QUAD(7, A12, A13, A14, A15);   // rows 28-31
  // epilogue pair: rows 32,33 (in A0,A1 since quad 4); slots 0,1 were last
  // read at quad 6, barrier of quad 7 intervened.
  ((float4*)&sh.ring[0][0])[tid] = A0;
  ((float4*)&sh.ring[1][0])[tid] = A1;
  SBAR_LDS();
  GATHER1(&sh.ring[0][0], DSTROW(32));
  GATHER1(&sh.ring[1][0], DSTROW(33));
#undef QUAD
#undef GATHER1
#undef SRCROW
#undef DSTROW
}

extern "C" void kernel_launch(void* const* d_in, const int* in_sizes, int n_in,
                              void* d_out, int out_size, void* d_ws, size_t ws_size,
                              hipStream_t stream) {
  const float* x    = (const float*)d_in[0];
  const float* v    = (const float*)d_in[1];
  const void*  mask = d_in[2];
  const float* rnd  = (const float*)d_in[3];

  float* xo = (float*)d_out;                  // B*C*L
  float* vo = xo + (size_t)BB * CC * LL;      // B*CV*L
  float* mo = vo + (size_t)BB * CVV * LL;     // B*1*L

  trimmer_kernel<<<BB * 2, 512, 0, stream>>>(x, v, mask, rnd, xo, vo, mo);
}

// Round 20
// 51.278 us; speedup vs baseline: 1.3190x; 1.1374x over previous
//
#include <hip/hip_runtime.h>
#include <stdint.h>

typedef unsigned long long ull;
typedef float fx4 __attribute__((ext_vector_type(4)));  // native vec for nt-store

#define BB 256
#define CC 64
#define CVV 4
#define LL 2048
#define NRB 34   // rows per block (68 / 2 blocks per batch)

// LDS-only barrier: orders ds ops across waves WITHOUT draining vmcnt.
#define SBAR_LDS() do { \
    asm volatile("s_waitcnt lgkmcnt(0)" ::: "memory"); \
    __builtin_amdgcn_s_barrier(); \
    __builtin_amdgcn_sched_barrier(0); \
  } while (0)

// Intra-thread compare-exchange of a pair.
#define CEP(A, B, descblk) do { \
    ull _lo = (A < B) ? A : B; \
    ull _hi = (A < B) ? B : A; \
    A = (descblk) ? _hi : _lo; \
    B = (descblk) ? _lo : _hi; \
  } while (0)

// Shuffle compare-exchange: partner via lane XOR; keep max iff keepmax.
#define CES(E, s4, keepmax) do { \
    ull _p = __shfl_xor(E, (s4), 64); \
    E = (keepmax) ? ((E >= _p) ? E : _p) : ((E <= _p) ? E : _p); \
  } while (0)

__device__ __forceinline__ ull mkkey(bool m, float r, int i) {
  float rf = m ? -1.0f : r;
  unsigned u = __float_as_uint(rf);
  u = (u & 0x80000000u) ? ~u : (u | 0x80000000u);  // order-preserving map
  return ((ull)u << 32) | (unsigned)(LL - 1 - i);
}

// ---------------------------------------------------------------------------
// Grid 512 = 2 blocks per batch, 512 threads -> 2 blocks/CU, 16 waves/CU.
// Phase 1: register/shuffle bitonic argsort (R17/R18): thread t owns elements
//   4t..4t+3 in regs; strides 1,2 intra-thread; 4..128 shfl_xor; 256/512/1024
//   via padded-LDS exchange. The exchange buffer aliases ring slots 4-6, and
//   rows 0-3 are PRE-STAGED into ring slots 0-3 BEFORE the sort — the
//   ds_write forces the prefetch loads to complete (compiler cannot sink
//   them), so ~16 MB chip-wide of HBM reads genuinely stream under the sort,
//   and gather iters 0-1 find their rows already in LDS.
// Phase 2: 17 pair-iters: stage rows 2i+4,2i+5 (slots (2i+4)%8,(2i+5)%8 -
//   prev occupants gathered at iter i-2, two barriers back - safe), ONE
//   LDS-only barrier, gather rows 2i,2i+1 with NONTEMPORAL stores (outputs
//   are write-once: nt avoids L2 write-allocate evicting warm input lines).
//   Reload distance 16, compiler-tracked vmcnt, no drains.
// ---------------------------------------------------------------------------
__global__ __launch_bounds__(512) void trimmer_kernel(
    const float* __restrict__ x, const float* __restrict__ v,
    const void* __restrict__ mask, const float* __restrict__ rnd,
    float* __restrict__ xo, float* __restrict__ vo, float* __restrict__ mo) {
  __shared__ float ring[8][LL];   // 64 KB; sort exchange aliases slots 4-6
  __shared__ int wcnt[8];
  ull* const xch = (ull*)&ring[4][0];  // 2560 ull = 20 KB < 24 KB (slots 4-6)

  const int b = blockIdx.x >> 1;
  const int g = blockIdx.x & 1;
  const int tid = threadIdx.x;
  const int w = tid >> 6;
  const int lane = tid & 63;
  const unsigned* m32 = (const unsigned*)mask;

  // --- scalar-load layout detect (uniform address -> s_load) ---
  unsigned acc = 0;
#pragma unroll
  for (int j = 0; j < 16; ++j) acc |= m32[(size_t)b * 512 + j];
  const bool is_byte = (acc != 0u) && (acc != 1u) && (acc != 0x3F800000u);

  // --- rand + mask for this thread's 4 elements ---
  const float4 rv4 = ((const float4*)(rnd + (size_t)b * LL))[tid];
  unsigned mq0, mq1, mq2, mq3;
  if (is_byte) {
    unsigned word = m32[(size_t)b * 512 + tid];   // bytes 4t..4t+3
    mq0 = word & 0xFFu; mq1 = (word >> 8) & 0xFFu;
    mq2 = (word >> 16) & 0xFFu; mq3 = (word >> 24) & 0xFFu;
  } else {
    int4 t4 = ((const int4*)m32)[(size_t)b * 512 + tid];  // ints 4t..4t+3
    mq0 = t4.x; mq1 = t4.y; mq2 = t4.z; mq3 = t4.w;
  }

  const float* const xs = x + (size_t)b * CC * LL;
  const float* const vs = v + (size_t)b * CVV * LL;
  float* const xd = xo + (size_t)b * CC * LL;
  float* const vd = vo + (size_t)b * CVV * LL;

#define SRCROW(rr) ((g * NRB + (rr)) < CC \
    ? xs + (size_t)(g * NRB + (rr)) * LL \
    : vs + (size_t)(g * NRB + (rr) - CC) * LL)
#define DSTROW(rr) ((g * NRB + (rr)) < CC \
    ? xd + (size_t)(g * NRB + (rr)) * LL \
    : vd + (size_t)(g * NRB + (rr) - CC) * LL)

  // --- prefetch rows 0..15 into named registers ---
  float4 A0  = ((const float4*)SRCROW(0))[tid];
  float4 A1  = ((const float4*)SRCROW(1))[tid];
  float4 A2  = ((const float4*)SRCROW(2))[tid];
  float4 A3  = ((const float4*)SRCROW(3))[tid];
  float4 A4  = ((const float4*)SRCROW(4))[tid];
  float4 A5  = ((const float4*)SRCROW(5))[tid];
  float4 A6  = ((const float4*)SRCROW(6))[tid];
  float4 A7  = ((const float4*)SRCROW(7))[tid];
  float4 A8  = ((const float4*)SRCROW(8))[tid];
  float4 A9  = ((const float4*)SRCROW(9))[tid];
  float4 A10 = ((const float4*)SRCROW(10))[tid];
  float4 A11 = ((const float4*)SRCROW(11))[tid];
  float4 A12 = ((const float4*)SRCROW(12))[tid];
  float4 A13 = ((const float4*)SRCROW(13))[tid];
  float4 A14 = ((const float4*)SRCROW(14))[tid];
  float4 A15 = ((const float4*)SRCROW(15))[tid];

  // --- build keys in registers; count masked ---
  ull e0 = mkkey(mq0 != 0u, rv4.x, 4 * tid + 0);
  ull e1 = mkkey(mq1 != 0u, rv4.y, 4 * tid + 1);
  ull e2 = mkkey(mq2 != 0u, rv4.z, 4 * tid + 2);
  ull e3 = mkkey(mq3 != 0u, rv4.w, 4 * tid + 3);
  int local = (mq0 != 0u) + (mq1 != 0u) + (mq2 != 0u) + (mq3 != 0u);
#pragma unroll
  for (int off = 32; off > 0; off >>= 1) local += __shfl_down(local, off, 64);
  if (lane == 0) wcnt[w] = local;

  // --- PRE-STAGE rows 0-3 into ring slots 0-3 (forces loads to complete;
  //     sort exchange lives in slots 4-6, no clash). Reload regs 0-3 with
  //     rows 16-19 (loads issue now, complete under the sort). ---
  ((float4*)&ring[0][0])[tid] = A0;
  ((float4*)&ring[1][0])[tid] = A1;
  ((float4*)&ring[2][0])[tid] = A2;
  ((float4*)&ring[3][0])[tid] = A3;
  A0 = ((const float4*)SRCROW(16))[tid];
  A1 = ((const float4*)SRCROW(17))[tid];
  A2 = ((const float4*)SRCROW(18))[tid];
  A3 = ((const float4*)SRCROW(19))[tid];

  // ================= bitonic sort, descending, in registers ================
  CEP(e0, e1, true);
  CEP(e2, e3, false);
  {
    const bool d = (tid & 1) == 0;
    CEP(e0, e2, d); CEP(e1, e3, d);
    CEP(e0, e1, d); CEP(e2, e3, d);
  }
  for (int size = 8; size <= 256; size <<= 1) {
    const bool d = (tid & (size >> 2)) == 0;
    for (int s4 = size >> 3; s4 >= 1; s4 >>= 1) {
      const bool keepmax = (d == ((tid & s4) == 0));
      CES(e0, s4, keepmax); CES(e1, s4, keepmax);
      CES(e2, s4, keepmax); CES(e3, s4, keepmax);
    }
    CEP(e0, e2, d); CEP(e1, e3, d);
    CEP(e0, e1, d); CEP(e2, e3, d);
  }
  for (int size = 512; size <= 2048; size <<= 1) {
    const bool d = (tid & (size >> 2)) == 0;
    for (int s4 = size >> 3; s4 >= 64; s4 >>= 1) {  // stride = 4*s4 >= 256
      ull* kp = &xch[5 * tid];                      // padded: bank 10t%32
      kp[0] = e0; kp[1] = e1; kp[2] = e2; kp[3] = e3;
      SBAR_LDS();
      const ull* pp = &xch[5 * (tid ^ s4)];
      ull p0 = pp[0], p1 = pp[1], p2 = pp[2], p3 = pp[3];
      const bool keepmax = (d == ((tid & s4) == 0));
      e0 = keepmax ? ((e0 >= p0) ? e0 : p0) : ((e0 <= p0) ? e0 : p0);
      e1 = keepmax ? ((e1 >= p1) ? e1 : p1) : ((e1 <= p1) ? e1 : p1);
      e2 = keepmax ? ((e2 >= p2) ? e2 : p2) : ((e2 <= p2) ? e2 : p2);
      e3 = keepmax ? ((e3 >= p3) ? e3 : p3) : ((e3 <= p3) ? e3 : p3);
      SBAR_LDS();   // partner reads done before anyone's next write
    }
    for (int s4 = 32; s4 >= 1; s4 >>= 1) {
      const bool keepmax = (d == ((tid & s4) == 0));
      CES(e0, s4, keepmax); CES(e1, s4, keepmax);
      CES(e2, s4, keepmax); CES(e3, s4, keepmax);
    }
    CEP(e0, e2, d); CEP(e1, e3, d);
    CEP(e0, e1, d); CEP(e2, e3, d);
  }
  // ========================================================================
  // Sorted keys for output positions 4*tid..4*tid+3 are now e0..e3.

  const int cnt = wcnt[0] + wcnt[1] + wcnt[2] + wcnt[3] +
                  wcnt[4] + wcnt[5] + wcnt[6] + wcnt[7];
  const int maxlen = cnt > 1 ? cnt : 1;              // jnp.maximum(count, 1)
  const unsigned ordNeg1 = ~__float_as_uint(-1.0f);  // ord(-1.0)

#define EXT(E, k, SV, MF) do { \
    const int _j = 4 * tid + (k); \
    int _idx = (LL - 1) - (int)(unsigned)((E) & 0xFFFFFFFFull); \
    bool _masked = ((unsigned)((E) >> 32)) == ordNeg1; \
    bool _keep = _j < maxlen; \
    SV = _idx | (_keep ? (1 << 12) : 0); \
    MF = (_keep && _masked) ? 1.0f : 0.0f; \
  } while (0)
  int sv0, sv1, sv2, sv3; float mf0, mf1, mf2, mf3;
  EXT(e0, 0, sv0, mf0); EXT(e1, 1, sv1, mf1);
  EXT(e2, 2, sv2, mf2); EXT(e3, 3, sv3, mf3);
#undef EXT
  const int4 s = make_int4(sv0, sv1, sv2, sv3);
  if (g == 0) {
    fx4 mfv = {mf0, mf1, mf2, mf3};
    __builtin_nontemporal_store(mfv, (fx4*)(mo + (size_t)b * LL) + tid);
  }
  // Last xch read was followed by SBAR_LDS inside the exchange loop; the
  // pre-staged slots 0-3 are visible to all waves via those same barriers.

#define GATHER1(buf, dst) do { \
    const float* _bb = (buf); \
    fx4 o; \
    o.x = (s.x & (1 << 12)) ? _bb[s.x & 0x7FF] : 0.0f; \
    o.y = (s.y & (1 << 12)) ? _bb[s.y & 0x7FF] : 0.0f; \
    o.z = (s.z & (1 << 12)) ? _bb[s.z & 0x7FF] : 0.0f; \
    o.w = (s.w & (1 << 12)) ? _bb[s.w & 0x7FF] : 0.0f; \
    __builtin_nontemporal_store(o, (fx4*)(dst) + tid); \
  } while (0)

  // Pair-iter: stage rows 2i+4,2i+5 from regs (reload +16), ONE barrier,
  // gather rows 2i,2i+1. Slot (r)%8 reuse: prev occupant r-8 was gathered
  // at iter i-2 — two barriers before this stage. Rows 2i,2i+1 were staged
  // at iter i-2 (or pre-staged), lgkmcnt-drained at that iter's barrier.
#define PITER(ii, RA, RB) do { \
    constexpr int rs0 = 2 * (ii) + 4, rs1 = 2 * (ii) + 5; \
    if constexpr (rs0 < NRB) ((float4*)&ring[rs0 & 7][0])[tid] = RA; \
    if constexpr (rs1 < NRB) ((float4*)&ring[rs1 & 7][0])[tid] = RB; \
    if constexpr (rs0 + 16 < NRB) RA = ((const float4*)SRCROW(rs0 + 16))[tid]; \
    if constexpr (rs1 + 16 < NRB) RB = ((const float4*)SRCROW(rs1 + 16))[tid]; \
    SBAR_LDS(); \
    GATHER1(&ring[(2 * (ii)) & 7][0], DSTROW(2 * (ii))); \
    GATHER1(&ring[(2 * (ii) + 1) & 7][0], DSTROW(2 * (ii) + 1)); \
  } while (0)

  PITER(0,  A4,  A5);    // stage 4,5;  reload 20,21; gather 0,1
  PITER(1,  A6,  A7);    // stage 6,7;  reload 22,23; gather 2,3
  PITER(2,  A8,  A9);    // stage 8,9;  reload 24,25; gather 4,5
  PITER(3,  A10, A11);   // stage 10,11; reload 26,27; gather 6,7
  PITER(4,  A12, A13);   // stage 12,13; reload 28,29; gather 8,9
  PITER(5,  A14, A15);   // stage 14,15; reload 30,31; gather 10,11
  PITER(6,  A0,  A1);    // stage 16,17; reload 32,33; gather 12,13
  PITER(7,  A2,  A3);    // stage 18,19; gather 14,15
  PITER(8,  A4,  A5);    // stage 20,21; gather 16,17
  PITER(9,  A6,  A7);    // stage 22,23; gather 18,19
  PITER(10, A8,  A9);    // stage 24,25; gather 20,21
  PITER(11, A10, A11);   // stage 26,27; gather 22,23
  PITER(12, A12, A13);   // stage 28,29; gather 24,25
  PITER(13, A14, A15);   // stage 30,31; gather 26,27
  PITER(14, A0,  A1);    // stage 32,33; gather 28,29
  PITER(15, A2,  A3);    // (no stage);  gather 30,31
  PITER(16, A4,  A5);    // (no stage);  gather 32,33
#undef PITER
#undef GATHER1
#undef SRCROW
#undef DSTROW
}

extern "C" void kernel_launch(void* const* d_in, const int* in_sizes, int n_in,
                              void* d_out, int out_size, void* d_ws, size_t ws_size,
                              hipStream_t stream) {
  const float* x    = (const float*)d_in[0];
  const float* v    = (const float*)d_in[1];
  const void*  mask = d_in[2];
  const float* rnd  = (const float*)d_in[3];

  float* xo = (float*)d_out;                  // B*C*L
  float* vo = xo + (size_t)BB * CC * LL;      // B*CV*L
  float* mo = vo + (size_t)BB * CVV * LL;     // B*1*L

  trimmer_kernel<<<BB * 2, 512, 0, stream>>>(x, v, mask, rnd, xo, vo, mo);
}